// Round 8
// baseline (290.917 us; speedup 1.0000x reference)
//
#include <hip/hip_runtime.h>

// TangentSpaceLoss: loss = (1/B^2) sum_ij softmax_j(E E^T)_ij * ||v_i - v_j||^2
// B=8192, G=512, D=64.
//
// R7 post-mortem: atomic-free slab had a write RACE — waves sharing the same
// wi half (waves 0&2, 1&3) both stored myslab[row] holding only their wj-half
// of the i-side partials (absmax 1.4e-9). R8 fix: unified LDS combine —
// zi/ni go to LDS plane [wj][row], zj/nj to plane [wi][col] (disjoint by
// construction: plane index = coordinate being summed), one barrier, 256
// threads fold planes -> exclusive coalesced slab stores. Still ZERO global
// atomics in k_mega (R6 theory under test: 2.1M device-scope atomics =
// the ~211 MB mystery WRITE traffic).
//   G tile: fp16 MFMA, K=512, reg-prefetch + LDS dbuf (G phase first)
//   S tile: fp16 MFMA + residual (E=h+r; s=hh'+hr'+rh', err ~1e-4), fused
//           into epilogue im-major
// Selection: s > min(ne_i,ne_j)-32 (safe superset; neglected mass 2.7e-11
// << 5.4e-10 tol). Softmax shift ne_i; diagonal w=1, wd=0 -> +1.0 in k_red.
// Slab layout per block (512 f32): [0:128) zi, [128:256) ni, [256:384) zj,
// [384:512) nj. k_red folds the 65 contributing slabs per row.

#define B_CELLS 8192
#define G_GENES 512
#define D_LAT   64
#define SEL_T   32.0f
#define SR      72          // LDS row stride in halfs

typedef _Float16 half8 __attribute__((ext_vector_type(8)));
typedef float    f32x4 __attribute__((ext_vector_type(4)));

#define MFMA16(a, b, c) __builtin_amdgcn_mfma_f32_16x16x32_f16(a, b, c, 0, 0, 0)

// ---------------- K1: norms + fp16 (h + residual) casts -----------------
__global__ __launch_bounds__(256) void k_prep(
    const float* __restrict__ V, const float* __restrict__ E,
    float* __restrict__ n, float* __restrict__ ne,
    _Float16* __restrict__ Eh, _Float16* __restrict__ Er,
    _Float16* __restrict__ Vh) {
    int row  = (blockIdx.x << 2) + (threadIdx.x >> 6);
    int lane = threadIdx.x & 63;
    const float* vr = V + (size_t)row * G_GENES;
    _Float16* vh = Vh + (size_t)row * G_GENES;
    float sn = 0.f;
#pragma unroll
    for (int k = 0; k < 8; ++k) {
        float x = vr[k * 64 + lane];
        vh[k * 64 + lane] = (_Float16)x;
        sn += x * x;
    }
    float el = E[row * D_LAT + lane];
    _Float16 hx = (_Float16)el;
    Eh[row * D_LAT + lane] = hx;
    Er[row * D_LAT + lane] = (_Float16)(el - (float)hx);
    float se = el * el;
#pragma unroll
    for (int m = 1; m < 64; m <<= 1) {
        sn += __shfl_xor(sn, m, 64);
        se += __shfl_xor(se, m, 64);
    }
    if (lane == 0) { n[row] = sn; ne[row] = se; }
}

// ---------------- K2: fused 128x128 tile kernel, atomic-free ------------
// 256 thr = 4 waves in 2x2 grid; wave tile 64x64 = 4x4 MFMA tiles.
__global__ __launch_bounds__(256, 2) void k_mega(
    const _Float16* __restrict__ Eh, const _Float16* __restrict__ Er,
    const _Float16* __restrict__ Vh,
    const float* __restrict__ ne, const float* __restrict__ nrm,
    float* __restrict__ slab) {
    // triangular decode: blk -> (bx <= by)
    int blk = blockIdx.x;
    int by = (int)((sqrtf(8.f * (float)blk + 1.f) - 1.f) * 0.5f);
    while ((by + 1) * (by + 2) / 2 <= blk) ++by;
    while (by * (by + 1) / 2 > blk) --by;
    int bx = blk - by * (by + 1) / 2;
    int i0 = bx << 7, j0 = by << 7;
    bool diag = (bx == by);
    float* myslab = slab + (size_t)blk * 512;

    __shared__ __align__(16) _Float16 sA[2][128 * SR];
    __shared__ __align__(16) _Float16 sB[2][128 * SR];
    __shared__ float sNeI[128], sNeJ[128], sNI[128], sNJ[128];

    int tid = threadIdx.x;
    int wave = tid >> 6, lane = tid & 63;
    int m = lane & 15, quad = lane >> 4;
    int wi = wave & 1, wj = wave >> 1;
    int ia = (wi << 6) + m;              // a rows = ia + im*16
    int ja = (wj << 6) + m;              // b rows (C cols) = ja + jn*16

    const uint4* gVa = (const uint4*)(Vh + (size_t)i0 * G_GENES);  // 64 u4/row
    const uint4* gVb = (const uint4*)(Vh + (size_t)j0 * G_GENES);

    // prefetch chunk 0 into regs
    uint4 pa[4], pb[4];
#pragma unroll
    for (int k = 0; k < 4; ++k) {
        int t = tid + (k << 8);
        int r = t >> 3, cc = t & 7;
        pa[k] = gVa[(size_t)r * 64 + cc];
        pb[k] = gVb[(size_t)r * 64 + cc];
    }
    if (tid < 128) { sNeI[tid] = ne[i0 + tid]; sNI[tid] = nrm[i0 + tid]; }
    else { sNeJ[tid - 128] = ne[j0 + tid - 128]; sNJ[tid - 128] = nrm[j0 + tid - 128]; }

    // write chunk 0, prefetch chunk 1
    {
        uint4* la = (uint4*)sA[0]; uint4* lb = (uint4*)sB[0];
#pragma unroll
        for (int k = 0; k < 4; ++k) {
            int t = tid + (k << 8);
            int r = t >> 3, cc = t & 7;
            la[r * 9 + cc] = pa[k];
            lb[r * 9 + cc] = pb[k];
        }
#pragma unroll
        for (int k = 0; k < 4; ++k) {
            int t = tid + (k << 8);
            int r = t >> 3, cc = t & 7;
            pa[k] = gVa[(size_t)r * 64 + 8 + cc];
            pb[k] = gVb[(size_t)r * 64 + 8 + cc];
        }
    }
    __syncthreads();

    // ---- G phase: K=512 in 8 chunks, reg-prefetch + LDS dbuf ----
    f32x4 gacc[4][4] = {};
    for (int c = 0; c < 8; ++c) {
        const _Float16* A  = sA[c & 1];
        const _Float16* Bt = sB[c & 1];
        if (c < 7) {
            uint4* la = (uint4*)sA[(c + 1) & 1];
            uint4* lb = (uint4*)sB[(c + 1) & 1];
#pragma unroll
            for (int k = 0; k < 4; ++k) {
                int t = tid + (k << 8);
                int r = t >> 3, cc = t & 7;
                la[r * 9 + cc] = pa[k];
                lb[r * 9 + cc] = pb[k];
            }
            if (c < 6) {
#pragma unroll
                for (int k = 0; k < 4; ++k) {
                    int t = tid + (k << 8);
                    int r = t >> 3, cc = t & 7;
                    pa[k] = gVa[(size_t)r * 64 + (c + 2) * 8 + cc];
                    pb[k] = gVb[(size_t)r * 64 + (c + 2) * 8 + cc];
                }
            }
        }
        half8 va[4][2];
#pragma unroll
        for (int im = 0; im < 4; ++im) {
            int row = ia + im * 16;
            va[im][0] = *(const half8*)(A + row * SR + quad * 8);
            va[im][1] = *(const half8*)(A + row * SR + 32 + quad * 8);
        }
#pragma unroll
        for (int jn = 0; jn < 4; ++jn) {
            int col = ja + jn * 16;
            half8 vb0 = *(const half8*)(Bt + col * SR + quad * 8);
            half8 vb1 = *(const half8*)(Bt + col * SR + 32 + quad * 8);
#pragma unroll
            for (int im = 0; im < 4; ++im) {
                gacc[im][jn] = MFMA16(va[im][0], vb0, gacc[im][jn]);
                gacc[im][jn] = MFMA16(va[im][1], vb1, gacc[im][jn]);
            }
        }
        if (c < 7) __syncthreads();
    }

    // LDS scratch for cross-wave combine (sA[0] dead after c=6 barrier;
    // c=7 reads only sA[1]/sB[1]):
    // scr[  0+wj*128+row]: zi plane   scr[256+wj*128+row]: ni plane
    // scr[512+wi*128+col]: zj plane   scr[768+wi*128+col]: nj plane
    float* scr = (float*)sA;

    // ---- fused S phase + epilogue, im-major; zero global atomics ----
    float zj[4] = {}, nj_[4] = {};
    {
        const _Float16* gAh = Eh + (size_t)i0 * D_LAT;
        const _Float16* gAr = Er + (size_t)i0 * D_LAT;
        const _Float16* gBh = Eh + (size_t)j0 * D_LAT;
        const _Float16* gBr = Er + (size_t)j0 * D_LAT;
#pragma unroll
        for (int im = 0; im < 4; ++im) {
            int row = ia + im * 16;
            half8 ah0 = *(const half8*)(gAh + (size_t)row * 64 + quad * 8);
            half8 ah1 = *(const half8*)(gAh + (size_t)row * 64 + 32 + quad * 8);
            half8 ar0 = *(const half8*)(gAr + (size_t)row * 64 + quad * 8);
            half8 ar1 = *(const half8*)(gAr + (size_t)row * 64 + 32 + quad * 8);
            f32x4 zi4 = {0.f, 0.f, 0.f, 0.f};
            f32x4 ni4 = {0.f, 0.f, 0.f, 0.f};
#pragma unroll
            for (int jn = 0; jn < 4; ++jn) {
                int col = ja + jn * 16;
                half8 bh0 = *(const half8*)(gBh + (size_t)col * 64 + quad * 8);
                half8 bh1 = *(const half8*)(gBh + (size_t)col * 64 + 32 + quad * 8);
                half8 br0 = *(const half8*)(gBr + (size_t)col * 64 + quad * 8);
                half8 br1 = *(const half8*)(gBr + (size_t)col * 64 + 32 + quad * 8);
                f32x4 acc = {0.f, 0.f, 0.f, 0.f};
                acc = MFMA16(ah0, bh0, acc);
                acc = MFMA16(ah1, bh1, acc);
                acc = MFMA16(ah0, br0, acc);
                acc = MFMA16(ah1, br1, acc);
                acc = MFMA16(ar0, bh0, acc);
                acc = MFMA16(ar1, bh1, acc);
                int jl = (wj << 6) + jn * 16 + m;
                int jg = j0 + jl;
                float nej = sNeJ[jl], nnj = sNJ[jl];
                f32x4 g4 = gacc[im][jn];
#pragma unroll
                for (int r = 0; r < 4; ++r) {
                    int il = (wi << 6) + im * 16 + quad * 4 + r;
                    int ig = i0 + il;
                    float nei = sNeI[il], nni = sNI[il];
                    float s = acc[r];
                    bool pred = (s > fminf(nei, nej) - SEL_T) && (!diag || ig < jg);
                    if (pred) {
                        float wiw = __expf(s - nei);
                        float wjw = __expf(s - nej);
                        float wd = nni + nnj - 2.f * g4[r];
                        zi4[r] += wiw;  ni4[r] += wiw * wd;
                        zj[jn] += wjw;  nj_[jn] += wjw * wd;
                    }
                }
            }
            // i-side: reduce over the 16 m-lanes, write wj-plane to LDS
#pragma unroll
            for (int msk = 1; msk < 16; msk <<= 1) {
#pragma unroll
                for (int r = 0; r < 4; ++r) {
                    zi4[r] += __shfl_xor(zi4[r], msk, 64);
                    ni4[r] += __shfl_xor(ni4[r], msk, 64);
                }
            }
            if (m == 0) {
                int row0 = (wi << 6) + im * 16 + quad * 4;
                *(f32x4*)(scr + (wj << 7) + row0)       = zi4;
                *(f32x4*)(scr + 256 + (wj << 7) + row0) = ni4;
            }
        }
    }

    // ---- j-side: reduce over quads, write wi-plane to LDS ----
#pragma unroll
    for (int msk = 16; msk < 64; msk <<= 1) {
#pragma unroll
        for (int jn = 0; jn < 4; ++jn) {
            zj[jn]  += __shfl_xor(zj[jn],  msk, 64);
            nj_[jn] += __shfl_xor(nj_[jn], msk, 64);
        }
    }
    if (quad == 0) {
#pragma unroll
        for (int jn = 0; jn < 4; ++jn) {
            int jl = (wj << 6) + jn * 16 + m;
            scr[512 + (wi << 7) + jl] = zj[jn];
            scr[768 + (wi << 7) + jl] = nj_[jn];
        }
    }
    __syncthreads();

    // ---- fold planes, exclusive coalesced slab stores ----
    if (tid < 128) {
        myslab[tid]       = scr[tid]       + scr[128 + tid];
        myslab[128 + tid] = scr[256 + tid] + scr[384 + tid];
    } else {
        int cidx = tid - 128;
        myslab[256 + cidx] = scr[512 + cidx] + scr[640 + cidx];
        myslab[384 + cidx] = scr[768 + cidx] + scr[896 + cidx];
    }
}

// ---------------- K3: per-row fold of 65 slabs + block reduce -----------
__global__ __launch_bounds__(256) void k_red(
    const float* __restrict__ slab, double* __restrict__ part) {
    int r = (blockIdx.x << 8) + threadIdx.x;
    int b = r >> 7, off = r & 127;
    float z = 1.0f, nv = 0.0f;           // +1: diagonal w=1, wd=0
    for (int by = b; by < 64; ++by) {    // i-side: blocks (bx=b, by)
        const float* s = slab + (size_t)(((by * (by + 1)) >> 1) + b) * 512;
        z  += s[off];
        nv += s[128 + off];
    }
    int base = (b * (b + 1)) >> 1;       // j-side: blocks (bx, by=b)
    for (int bx = 0; bx <= b; ++bx) {
        const float* s = slab + (size_t)(base + bx) * 512;
        z  += s[256 + off];
        nv += s[384 + off];
    }
    __shared__ double sd[256];
    sd[threadIdx.x] = (double)nv / (double)z;
    __syncthreads();
    for (int st = 128; st > 0; st >>= 1) {
        if (threadIdx.x < st) sd[threadIdx.x] += sd[threadIdx.x + st];
        __syncthreads();
    }
    if (threadIdx.x == 0) part[blockIdx.x] = sd[0];
}

__global__ void k_final2(const double* __restrict__ part, float* __restrict__ out) {
    if (threadIdx.x == 0) {
        double a = 0.0;
        for (int k = 0; k < 32; ++k) a += part[k];
        out[0] = (float)(a / 67108864.0);              // / B^2
    }
}

// ---------------- host launcher -----------------------------------------
extern "C" void kernel_launch(void* const* d_in, const int* in_sizes, int n_in,
                              void* d_out, int out_size, void* d_ws, size_t ws_size,
                              hipStream_t stream) {
    const float* V = (const float*)d_in[0];   // [8192, 512] f32
    const float* E = (const float*)d_in[1];   // [8192, 64]  f32
    float* out = (float*)d_out;
    char* ws = (char*)d_ws;

    float*     n_   = (float*)(ws + 0);           // 32 KB
    float*     ne   = (float*)(ws + 32768);       // 32 KB
    _Float16*  Eh   = (_Float16*)(ws + 65536);    // 1 MB
    _Float16*  Er   = (_Float16*)(ws + 1114112);  // 1 MB
    _Float16*  Vh   = (_Float16*)(ws + 2162688);  // 8 MB
    float*     slab = (float*)(ws + 10551296);    // 2080*512*4 = 4.26 MB
    double*    part = (double*)(ws + 14811136);   // 256 B

    k_prep  <<<2048, 256, 0, stream>>>(V, E, n_, ne, Eh, Er, Vh);
    k_mega  <<<2080, 256, 0, stream>>>(Eh, Er, Vh, ne, n_, slab);
    k_red   <<<32, 256, 0, stream>>>(slab, part);
    k_final2<<<1, 64, 0, stream>>>(part, out);
}

// Round 9
// 198.927 us; speedup vs baseline: 1.4624x; 1.4624x over previous
//
#include <hip/hip_runtime.h>

// TangentSpaceLoss: loss = (1/B^2) sum_ij softmax_j(E E^T)_ij * ||v_i - v_j||^2
// B=8192, G=512, D=64.
//
// R8 post-mortem: atomic-free kernel kept WRITE~211MB => mystery traffic is
// NOT stores/atomics/spill; it tracks FETCH (likely L2 victim traffic from
// the streaming read misses). Kernel is latency-bound: 2 blocks/CU (75KB
// LDS), barrier/chunk. R9: zero-LDS gather design —
//   k_prep writes FRAGMENT-LINEAR layouts: VF[rt][kc][m][k'] (rt=row/16,
//   kc=k/32, m=row%16, k'=k%32), EFh/EFr same with kc in {0,1}. Every MFMA
//   fragment load in k_mega = one contiguous 1KB wave-load from L2/L3.
//   No LDS staging, no dbuf, NO barriers in the K-loop (2 barriers total).
//   LDS 6KB -> occupancy register-bound; waves self-overlap via 16
//   outstanding loads each.
//   G tile: fp16 MFMA K=512; S tile: fp16+residual (E=h+r, s=hh'+hr'+rh'),
//   fused epilogue (R8's verified LDS-plane combine, slab, k_red).
// Selection: s > min(ne_i,ne_j)-32 (safe superset). Softmax shift ne_i;
// diagonal w=1, wd=0 -> +1.0 in k_red.
// XCD band swizzle: blk = (id&7)*260 + (id>>3) gives each XCD a contiguous
// triangle band (2080 = 8*260) for L2 tile sharing. Perf-only heuristic.

#define SEL_T 32.0f

typedef _Float16 half8 __attribute__((ext_vector_type(8)));
typedef float    f32x4 __attribute__((ext_vector_type(4)));

#define MFMA16(a, b, c) __builtin_amdgcn_mfma_f32_16x16x32_f16(a, b, c, 0, 0, 0)

// ---------------- K1: norms + fragment-linear fp16 layouts --------------
// VF : [rt 512][kc 16][m 16][k' 32] halfs  (8 MB)
// EFh/EFr : [rt 512][kc 2][m 16][k' 32] halfs (1 MB each)
__global__ __launch_bounds__(256) void k_prep(
    const float* __restrict__ V, const float* __restrict__ E,
    float* __restrict__ n, float* __restrict__ ne,
    _Float16* __restrict__ VF, _Float16* __restrict__ EFh,
    _Float16* __restrict__ EFr) {
    int rt = blockIdx.x;                       // 512 row-tiles of 16 rows
    int tid = threadIdx.x, wave = tid >> 6, lane = tid & 63;
    // V: one row per wave-pass; lane l covers k in [l*8, l*8+8)
#pragma unroll
    for (int pass = 0; pass < 4; ++pass) {
        int rl = pass * 4 + wave;              // row_local 0..15
        int row = rt * 16 + rl;
        const float4* vr = (const float4*)(V + (size_t)row * 512);
        float4 x0 = vr[lane * 2], x1 = vr[lane * 2 + 1];
        half8 h;
        h[0] = (_Float16)x0.x; h[1] = (_Float16)x0.y;
        h[2] = (_Float16)x0.z; h[3] = (_Float16)x0.w;
        h[4] = (_Float16)x1.x; h[5] = (_Float16)x1.y;
        h[6] = (_Float16)x1.z; h[7] = (_Float16)x1.w;
        int kc = lane >> 2, q = lane & 3;      // k = kc*32 + q*8
        *(half8*)(VF + ((size_t)rt * 16 + kc) * 512 + rl * 32 + q * 8) = h;
        float sn = x0.x*x0.x + x0.y*x0.y + x0.z*x0.z + x0.w*x0.w
                 + x1.x*x1.x + x1.y*x1.y + x1.z*x1.z + x1.w*x1.w;
#pragma unroll
        for (int msk = 1; msk < 64; msk <<= 1) sn += __shfl_xor(sn, msk, 64);
        if (lane == 0) n[row] = sn;
    }
    // E: threads 0..127 (waves 0,1): rl = t>>3, u = t&7, k in [u*8, u*8+8)
    if (tid < 128) {
        int rl = tid >> 3, u = tid & 7;
        int row = rt * 16 + rl;
        const float4* er = (const float4*)(E + (size_t)row * 64);
        float4 x0 = er[u * 2], x1 = er[u * 2 + 1];
        float xf[8] = {x0.x, x0.y, x0.z, x0.w, x1.x, x1.y, x1.z, x1.w};
        half8 h, r;
        float se = 0.f;
#pragma unroll
        for (int k = 0; k < 8; ++k) {
            _Float16 hx = (_Float16)xf[k];
            h[k] = hx; r[k] = (_Float16)(xf[k] - (float)hx);
            se += xf[k] * xf[k];
        }
        int kc = u >> 2, q = u & 3;
        size_t off = ((size_t)rt * 2 + kc) * 512 + rl * 32 + q * 8;
        *(half8*)(EFh + off) = h;
        *(half8*)(EFr + off) = r;
        se += __shfl_xor(se, 1, 64);
        se += __shfl_xor(se, 2, 64);
        se += __shfl_xor(se, 4, 64);
        if (u == 0) ne[row] = se;
    }
}

// ---------------- K2: zero-LDS gather tile kernel -----------------------
// 256 thr = 4 waves in 2x2 grid; wave tile 64x64 = 4x4 MFMA tiles.
__global__ __launch_bounds__(256, 2) void k_mega(
    const _Float16* __restrict__ VF, const _Float16* __restrict__ EFh,
    const _Float16* __restrict__ EFr, const float* __restrict__ ne,
    const float* __restrict__ nrm, float* __restrict__ slab) {
    // XCD band swizzle + triangular decode: blk -> (bx <= by)
    int blk0 = blockIdx.x;
    int blk = (blk0 & 7) * 260 + (blk0 >> 3);
    int by = (int)((sqrtf(8.f * (float)blk + 1.f) - 1.f) * 0.5f);
    while ((by + 1) * (by + 2) / 2 <= blk) ++by;
    while (by * (by + 1) / 2 > blk) --by;
    int bx = blk - by * (by + 1) / 2;
    int i0 = bx << 7, j0 = by << 7;
    bool diag = (bx == by);
    float* myslab = slab + (size_t)blk * 512;

    __shared__ float sNeI[128], sNeJ[128], sNI[128], sNJ[128];
    __shared__ float scr[1024];

    int tid = threadIdx.x;
    if (tid < 128) { sNeI[tid] = ne[i0 + tid]; sNI[tid] = nrm[i0 + tid]; }
    else { sNeJ[tid - 128] = ne[j0 + tid - 128]; sNJ[tid - 128] = nrm[j0 + tid - 128]; }
    __syncthreads();

    int wave = tid >> 6, lane = tid & 63;
    int m = lane & 15, quad = lane >> 4;
    int wi = wave & 1, wj = wave >> 1;
    int rtA = (i0 >> 4) + wi * 4;            // + im
    int rtB = (j0 >> 4) + wj * 4;            // + jn
    size_t lo = (size_t)(m * 32 + quad * 8); // lane offset inside a 1KB frag

    // ---- G phase: K=512, 8 chunks of 64; no LDS, no barriers ----
    f32x4 gacc[4][4] = {};
    for (int c = 0; c < 8; ++c) {
        half8 va[4][2], vb[4][2];
#pragma unroll
        for (int im = 0; im < 4; ++im) {
            const _Float16* p = VF + ((size_t)(rtA + im) * 16 + 2 * c) * 512 + lo;
            va[im][0] = *(const half8*)(p);
            va[im][1] = *(const half8*)(p + 512);
        }
#pragma unroll
        for (int jn = 0; jn < 4; ++jn) {
            const _Float16* p = VF + ((size_t)(rtB + jn) * 16 + 2 * c) * 512 + lo;
            vb[jn][0] = *(const half8*)(p);
            vb[jn][1] = *(const half8*)(p + 512);
        }
#pragma unroll
        for (int jn = 0; jn < 4; ++jn)
#pragma unroll
            for (int im = 0; im < 4; ++im) {
                gacc[im][jn] = MFMA16(va[im][0], vb[jn][0], gacc[im][jn]);
                gacc[im][jn] = MFMA16(va[im][1], vb[jn][1], gacc[im][jn]);
            }
    }

    // ---- fused S phase + epilogue (R8-verified combine) ----
    float zj[4] = {}, nj_[4] = {};
#pragma unroll
    for (int im = 0; im < 4; ++im) {
        size_t ab = (size_t)(rtA + im) * 2 * 512 + lo;
        half8 ah0 = *(const half8*)(EFh + ab);
        half8 ah1 = *(const half8*)(EFh + ab + 512);
        half8 ar0 = *(const half8*)(EFr + ab);
        half8 ar1 = *(const half8*)(EFr + ab + 512);
        f32x4 zi4 = {0.f, 0.f, 0.f, 0.f};
        f32x4 ni4 = {0.f, 0.f, 0.f, 0.f};
#pragma unroll
        for (int jn = 0; jn < 4; ++jn) {
            size_t bb = (size_t)(rtB + jn) * 2 * 512 + lo;
            half8 bh0 = *(const half8*)(EFh + bb);
            half8 bh1 = *(const half8*)(EFh + bb + 512);
            half8 br0 = *(const half8*)(EFr + bb);
            half8 br1 = *(const half8*)(EFr + bb + 512);
            f32x4 acc = {0.f, 0.f, 0.f, 0.f};
            acc = MFMA16(ah0, bh0, acc);
            acc = MFMA16(ah1, bh1, acc);
            acc = MFMA16(ah0, br0, acc);
            acc = MFMA16(ah1, br1, acc);
            acc = MFMA16(ar0, bh0, acc);
            acc = MFMA16(ar1, bh1, acc);
            int jl = (wj << 6) + jn * 16 + m;
            int jg = j0 + jl;
            float nej = sNeJ[jl], nnj = sNJ[jl];
            f32x4 g4 = gacc[im][jn];
#pragma unroll
            for (int r = 0; r < 4; ++r) {
                int il = (wi << 6) + im * 16 + quad * 4 + r;
                int ig = i0 + il;
                float nei = sNeI[il], nni = sNI[il];
                float s = acc[r];
                bool pred = (s > fminf(nei, nej) - SEL_T) && (!diag || ig < jg);
                if (pred) {
                    float wiw = __expf(s - nei);
                    float wjw = __expf(s - nej);
                    float wd = nni + nnj - 2.f * g4[r];
                    zi4[r] += wiw;  ni4[r] += wiw * wd;
                    zj[jn] += wjw;  nj_[jn] += wjw * wd;
                }
            }
        }
        // i-side: reduce over 16 m-lanes, write wj-plane
#pragma unroll
        for (int msk = 1; msk < 16; msk <<= 1) {
#pragma unroll
            for (int r = 0; r < 4; ++r) {
                zi4[r] += __shfl_xor(zi4[r], msk, 64);
                ni4[r] += __shfl_xor(ni4[r], msk, 64);
            }
        }
        if (m == 0) {
            int row0 = (wi << 6) + im * 16 + quad * 4;
            *(f32x4*)(scr + (wj << 7) + row0)       = zi4;
            *(f32x4*)(scr + 256 + (wj << 7) + row0) = ni4;
        }
    }
    // j-side: reduce over quads, write wi-plane
#pragma unroll
    for (int msk = 16; msk < 64; msk <<= 1) {
#pragma unroll
        for (int jn = 0; jn < 4; ++jn) {
            zj[jn]  += __shfl_xor(zj[jn],  msk, 64);
            nj_[jn] += __shfl_xor(nj_[jn], msk, 64);
        }
    }
    if (quad == 0) {
#pragma unroll
        for (int jn = 0; jn < 4; ++jn) {
            int jl = (wj << 6) + jn * 16 + m;
            scr[512 + (wi << 7) + jl] = zj[jn];
            scr[768 + (wi << 7) + jl] = nj_[jn];
        }
    }
    __syncthreads();
    // fold planes -> exclusive coalesced slab stores
    if (tid < 128) {
        myslab[tid]       = scr[tid]       + scr[128 + tid];
        myslab[128 + tid] = scr[256 + tid] + scr[384 + tid];
    } else {
        int cidx = tid - 128;
        myslab[256 + cidx] = scr[512 + cidx] + scr[640 + cidx];
        myslab[384 + cidx] = scr[768 + cidx] + scr[896 + cidx];
    }
}

// ---------------- K3: per-row fold of 65 slabs + block reduce -----------
__global__ __launch_bounds__(256) void k_red(
    const float* __restrict__ slab, double* __restrict__ part) {
    int r = (blockIdx.x << 8) + threadIdx.x;
    int b = r >> 7, off = r & 127;
    float z = 1.0f, nv = 0.0f;           // +1: diagonal w=1, wd=0
    for (int by = b; by < 64; ++by) {    // i-side: blocks (bx=b, by)
        const float* s = slab + (size_t)(((by * (by + 1)) >> 1) + b) * 512;
        z  += s[off];
        nv += s[128 + off];
    }
    int base = (b * (b + 1)) >> 1;       // j-side: blocks (bx, by=b)
    for (int bx = 0; bx <= b; ++bx) {
        const float* s = slab + (size_t)(base + bx) * 512;
        z  += s[256 + off];
        nv += s[384 + off];
    }
    __shared__ double sd[256];
    sd[threadIdx.x] = (double)nv / (double)z;
    __syncthreads();
    for (int st = 128; st > 0; st >>= 1) {
        if (threadIdx.x < st) sd[threadIdx.x] += sd[threadIdx.x + st];
        __syncthreads();
    }
    if (threadIdx.x == 0) part[blockIdx.x] = sd[0];
}

__global__ void k_final2(const double* __restrict__ part, float* __restrict__ out) {
    if (threadIdx.x == 0) {
        double a = 0.0;
        for (int k = 0; k < 32; ++k) a += part[k];
        out[0] = (float)(a / 67108864.0);              // / B^2
    }
}

// ---------------- host launcher -----------------------------------------
extern "C" void kernel_launch(void* const* d_in, const int* in_sizes, int n_in,
                              void* d_out, int out_size, void* d_ws, size_t ws_size,
                              hipStream_t stream) {
    const float* V = (const float*)d_in[0];   // [8192, 512] f32
    const float* E = (const float*)d_in[1];   // [8192, 64]  f32
    float* out = (float*)d_out;
    char* ws = (char*)d_ws;

    float*     n_   = (float*)(ws + 0);           // 32 KB
    float*     ne   = (float*)(ws + 32768);       // 32 KB
    _Float16*  VF   = (_Float16*)(ws + 65536);    // 8 MB fragment-linear V
    _Float16*  EFh  = (_Float16*)(ws + 8454144);  // 1 MB fragment-linear Eh
    _Float16*  EFr  = (_Float16*)(ws + 9502720);  // 1 MB fragment-linear Er
    float*     slab = (float*)(ws + 10551296);    // 2080*512*4 = 4.26 MB
    double*    part = (double*)(ws + 14811136);   // 256 B

    k_prep  <<<512, 256, 0, stream>>>(V, E, n_, ne, VF, EFh, EFr);
    k_mega  <<<2080, 256, 0, stream>>>(VF, EFh, EFr, ne, n_, slab);
    k_red   <<<32, 256, 0, stream>>>(slab, part);
    k_final2<<<1, 64, 0, stream>>>(part, out);
}

// Round 10
// 195.729 us; speedup vs baseline: 1.4863x; 1.0163x over previous
//
#include <hip/hip_runtime.h>

// TangentSpaceLoss: loss = (1/B^2) sum_ij softmax_j(E E^T)_ij * ||v_i - v_j||^2
// B=8192, G=512, D=64.
//
// R9 post-mortem: zero-LDS fragment-gather fixed the phantom write traffic
// (WRITE 211->4.2 MB = slab only). k_mega now fragment-return-bound:
// 208 b128 loads/wave (~45us L1-return floor) at 3 waves/SIMD (144 unified
// regs). R10: (1) V in fp8 e4m3 -> G-phase fragment bytes HALVED (64 b128
// loads/wave, each feeding 2 K=32 fp8 MFMAs; g err ~0.25% of wd -> ~7e-11
// on loss, inside 5.4e-10 budget). (2) frag regs 64->32 allows
// __launch_bounds__(256,4) -> 4 waves/SIMD. (3) k_red+k_final merged via
// last-block completion counter (one less launch). (4) k_prep slab writes
// fully coalesced. E stays fp16 h+residual (s = hh'+hr'+rh', err ~1e-4,
// R9-proven layout and S-phase verbatim).
// Selection: s > min(ne_i,ne_j)-32 (safe superset). Softmax shift ne_i;
// diagonal w=1, wd=0 -> +1.0 in k_red.
//
// VF8 layout: [rt 512][c 8][m 16][q 4][kc 2][8B] -- lane (m,quad) reads 16B
// at m*64+quad*16; bytes 0-7 = k=c*64+q*8.. (kc0), 8-15 = c*64+32+q*8.. (kc1).
// EFh/EFr: [rt 512][kc 2][m 16][k' 32] halfs (R9 layout, unchanged).

#define SEL_T 32.0f

typedef _Float16 half8 __attribute__((ext_vector_type(8)));
typedef float    f32x4 __attribute__((ext_vector_type(4)));
typedef long     l2t   __attribute__((ext_vector_type(2)));

#define MFMA16(a, b, c) __builtin_amdgcn_mfma_f32_16x16x32_f16(a, b, c, 0, 0, 0)
#define MFMA8(a, b, c)  __builtin_amdgcn_mfma_f32_16x16x32_fp8_fp8(a, b, c, 0, 0, 0)

// ---------------- K1: norms + fp8 V + fp16 h/r E layouts ----------------
__global__ __launch_bounds__(256) void k_prep(
    const float* __restrict__ V, const float* __restrict__ E,
    float* __restrict__ n, float* __restrict__ ne,
    unsigned char* __restrict__ VF8, _Float16* __restrict__ EFh,
    _Float16* __restrict__ EFr, unsigned* __restrict__ cnt) {
    int rt = blockIdx.x;                       // 512 row-tiles of 16 rows
    int tid = threadIdx.x, wave = tid >> 6, lane = tid & 63;
    if (rt == 0 && tid == 0) *cnt = 0;
    int m = lane >> 2, q = lane & 3;
    int row = rt * 16 + m;
    const float* vr = V + (size_t)row * 512;
    float sn = 0.f;
#pragma unroll
    for (int it = 0; it < 2; ++it) {
        int c = wave + it * 4;                 // K-chunk of 64
        const float4* p0 = (const float4*)(vr + c * 64 + q * 8);
        const float4* p1 = (const float4*)(vr + c * 64 + 32 + q * 8);
        float4 a0 = p0[0], a1 = p0[1], b0 = p1[0], b1 = p1[1];
        int w0 = 0, w1 = 0, w2 = 0, w3 = 0;
        w0 = __builtin_amdgcn_cvt_pk_fp8_f32(a0.x, a0.y, w0, false);
        w0 = __builtin_amdgcn_cvt_pk_fp8_f32(a0.z, a0.w, w0, true);
        w1 = __builtin_amdgcn_cvt_pk_fp8_f32(a1.x, a1.y, w1, false);
        w1 = __builtin_amdgcn_cvt_pk_fp8_f32(a1.z, a1.w, w1, true);
        w2 = __builtin_amdgcn_cvt_pk_fp8_f32(b0.x, b0.y, w2, false);
        w2 = __builtin_amdgcn_cvt_pk_fp8_f32(b0.z, b0.w, w2, true);
        w3 = __builtin_amdgcn_cvt_pk_fp8_f32(b1.x, b1.y, w3, false);
        w3 = __builtin_amdgcn_cvt_pk_fp8_f32(b1.z, b1.w, w3, true);
        uint4 o;
        o.x = (unsigned)w0; o.y = (unsigned)w1;
        o.z = (unsigned)w2; o.w = (unsigned)w3;
        // coalesced: wave writes one contiguous 1KB c-slab
        *(uint4*)(VF8 + (((size_t)rt * 8 + c) << 10) + lane * 16) = o;
        sn += a0.x*a0.x + a0.y*a0.y + a0.z*a0.z + a0.w*a0.w
            + a1.x*a1.x + a1.y*a1.y + a1.z*a1.z + a1.w*a1.w
            + b0.x*b0.x + b0.y*b0.y + b0.z*b0.z + b0.w*b0.w
            + b1.x*b1.x + b1.y*b1.y + b1.z*b1.z + b1.w*b1.w;
    }
    __shared__ float sred[4][64];
    sred[wave][lane] = sn;
    __syncthreads();
    if (tid < 16) {
        float s = 0.f;
#pragma unroll
        for (int w = 0; w < 4; ++w)
#pragma unroll
            for (int qq = 0; qq < 4; ++qq) s += sred[w][tid * 4 + qq];
        n[rt * 16 + tid] = s;
    }
    // E: threads 0..127 (R9-verbatim): rl = t>>3, u = t&7, k in [u*8, u*8+8)
    if (tid < 128) {
        int rl = tid >> 3, u = tid & 7;
        int erow = rt * 16 + rl;
        const float4* er = (const float4*)(E + (size_t)erow * 64);
        float4 x0 = er[u * 2], x1 = er[u * 2 + 1];
        float xf[8] = {x0.x, x0.y, x0.z, x0.w, x1.x, x1.y, x1.z, x1.w};
        half8 h, r;
        float se = 0.f;
#pragma unroll
        for (int k = 0; k < 8; ++k) {
            _Float16 hx = (_Float16)xf[k];
            h[k] = hx; r[k] = (_Float16)(xf[k] - (float)hx);
            se += xf[k] * xf[k];
        }
        int kc = u >> 2, qq = u & 3;
        size_t off = ((size_t)rt * 2 + kc) * 512 + rl * 32 + qq * 8;
        *(half8*)(EFh + off) = h;
        *(half8*)(EFr + off) = r;
        se += __shfl_xor(se, 1, 64);
        se += __shfl_xor(se, 2, 64);
        se += __shfl_xor(se, 4, 64);
        if (u == 0) ne[erow] = se;
    }
}

// ---------------- K2: zero-LDS gather tile kernel (fp8 G) ---------------
// 256 thr = 4 waves in 2x2 grid; wave tile 64x64 = 4x4 MFMA tiles.
__global__ __launch_bounds__(256, 4) void k_mega(
    const unsigned char* __restrict__ VF8, const _Float16* __restrict__ EFh,
    const _Float16* __restrict__ EFr, const float* __restrict__ ne,
    const float* __restrict__ nrm, float* __restrict__ slab) {
    // XCD band swizzle + triangular decode: blk -> (bx <= by)
    int blk0 = blockIdx.x;
    int blk = (blk0 & 7) * 260 + (blk0 >> 3);
    int by = (int)((sqrtf(8.f * (float)blk + 1.f) - 1.f) * 0.5f);
    while ((by + 1) * (by + 2) / 2 <= blk) ++by;
    while (by * (by + 1) / 2 > blk) --by;
    int bx = blk - by * (by + 1) / 2;
    int i0 = bx << 7, j0 = by << 7;
    bool diag = (bx == by);
    float* myslab = slab + (size_t)blk * 512;

    __shared__ float sNeI[128], sNeJ[128], sNI[128], sNJ[128];
    __shared__ float scr[1024];

    int tid = threadIdx.x;
    if (tid < 128) { sNeI[tid] = ne[i0 + tid]; sNI[tid] = nrm[i0 + tid]; }
    else { sNeJ[tid - 128] = ne[j0 + tid - 128]; sNJ[tid - 128] = nrm[j0 + tid - 128]; }
    __syncthreads();

    int wave = tid >> 6, lane = tid & 63;
    int m = lane & 15, quad = lane >> 4;
    int wi = wave & 1, wj = wave >> 1;
    int rtA = (i0 >> 4) + wi * 4;            // + im
    int rtB = (j0 >> 4) + wj * 4;            // + jn
    size_t loH = (size_t)(m * 32 + quad * 8);   // halfs (E frags)
    size_t loB = (size_t)(m * 64 + quad * 16);  // bytes (V fp8 frags)

    // ---- G phase: K=512, 8 chunks of 64; fp8, no LDS, no barriers ----
    f32x4 gacc[4][4] = {};
    for (int c = 0; c < 8; ++c) {
        l2t a[4], b[4];
#pragma unroll
        for (int im = 0; im < 4; ++im)
            a[im] = *(const l2t*)(VF8 + (((size_t)(rtA + im) * 8 + c) << 10) + loB);
#pragma unroll
        for (int jn = 0; jn < 4; ++jn)
            b[jn] = *(const l2t*)(VF8 + (((size_t)(rtB + jn) * 8 + c) << 10) + loB);
#pragma unroll
        for (int jn = 0; jn < 4; ++jn)
#pragma unroll
            for (int im = 0; im < 4; ++im) {
                gacc[im][jn] = MFMA8(a[im][0], b[jn][0], gacc[im][jn]);
                gacc[im][jn] = MFMA8(a[im][1], b[jn][1], gacc[im][jn]);
            }
    }

    // ---- fused S phase + epilogue (R9-verbatim) ----
    float zj[4] = {}, nj_[4] = {};
#pragma unroll
    for (int im = 0; im < 4; ++im) {
        size_t ab = (size_t)(rtA + im) * 2 * 512 + loH;
        half8 ah0 = *(const half8*)(EFh + ab);
        half8 ah1 = *(const half8*)(EFh + ab + 512);
        half8 ar0 = *(const half8*)(EFr + ab);
        half8 ar1 = *(const half8*)(EFr + ab + 512);
        f32x4 zi4 = {0.f, 0.f, 0.f, 0.f};
        f32x4 ni4 = {0.f, 0.f, 0.f, 0.f};
#pragma unroll
        for (int jn = 0; jn < 4; ++jn) {
            size_t bb = (size_t)(rtB + jn) * 2 * 512 + loH;
            half8 bh0 = *(const half8*)(EFh + bb);
            half8 bh1 = *(const half8*)(EFh + bb + 512);
            half8 br0 = *(const half8*)(EFr + bb);
            half8 br1 = *(const half8*)(EFr + bb + 512);
            f32x4 acc = {0.f, 0.f, 0.f, 0.f};
            acc = MFMA16(ah0, bh0, acc);
            acc = MFMA16(ah1, bh1, acc);
            acc = MFMA16(ah0, br0, acc);
            acc = MFMA16(ah1, br1, acc);
            acc = MFMA16(ar0, bh0, acc);
            acc = MFMA16(ar1, bh1, acc);
            int jl = (wj << 6) + jn * 16 + m;
            int jg = j0 + jl;
            float nej = sNeJ[jl], nnj = sNJ[jl];
            f32x4 g4 = gacc[im][jn];
#pragma unroll
            for (int r = 0; r < 4; ++r) {
                int il = (wi << 6) + im * 16 + quad * 4 + r;
                int ig = i0 + il;
                float nei = sNeI[il], nni = sNI[il];
                float s = acc[r];
                bool pred = (s > fminf(nei, nej) - SEL_T) && (!diag || ig < jg);
                if (pred) {
                    float wiw = __expf(s - nei);
                    float wjw = __expf(s - nej);
                    float wd = nni + nnj - 2.f * g4[r];
                    zi4[r] += wiw;  ni4[r] += wiw * wd;
                    zj[jn] += wjw;  nj_[jn] += wjw * wd;
                }
            }
        }
        // i-side: reduce over 16 m-lanes, write wj-plane
#pragma unroll
        for (int msk = 1; msk < 16; msk <<= 1) {
#pragma unroll
            for (int r = 0; r < 4; ++r) {
                zi4[r] += __shfl_xor(zi4[r], msk, 64);
                ni4[r] += __shfl_xor(ni4[r], msk, 64);
            }
        }
        if (m == 0) {
            int row0 = (wi << 6) + im * 16 + quad * 4;
            *(f32x4*)(scr + (wj << 7) + row0)       = zi4;
            *(f32x4*)(scr + 256 + (wj << 7) + row0) = ni4;
        }
    }
    // j-side: reduce over quads, write wi-plane
#pragma unroll
    for (int msk = 16; msk < 64; msk <<= 1) {
#pragma unroll
        for (int jn = 0; jn < 4; ++jn) {
            zj[jn]  += __shfl_xor(zj[jn],  msk, 64);
            nj_[jn] += __shfl_xor(nj_[jn], msk, 64);
        }
    }
    if (quad == 0) {
#pragma unroll
        for (int jn = 0; jn < 4; ++jn) {
            int jl = (wj << 6) + jn * 16 + m;
            scr[512 + (wi << 7) + jl] = zj[jn];
            scr[768 + (wi << 7) + jl] = nj_[jn];
        }
    }
    __syncthreads();
    // fold planes -> exclusive coalesced slab stores
    if (tid < 128) {
        myslab[tid]       = scr[tid]       + scr[128 + tid];
        myslab[128 + tid] = scr[256 + tid] + scr[384 + tid];
    } else {
        int cidx = tid - 128;
        myslab[256 + cidx] = scr[512 + cidx] + scr[640 + cidx];
        myslab[384 + cidx] = scr[768 + cidx] + scr[896 + cidx];
    }
}

// ------- K3: slab fold + reduce + last-block final (one launch) ---------
__global__ __launch_bounds__(256) void k_red(
    const float* __restrict__ slab, double* __restrict__ part,
    unsigned* __restrict__ cnt, float* __restrict__ out) {
    int r = (blockIdx.x << 8) + threadIdx.x;
    int b = r >> 7, off = r & 127;
    float z = 1.0f, nv = 0.0f;           // +1: diagonal w=1, wd=0
    for (int by = b; by < 64; ++by) {    // i-side: blocks (bx=b, by)
        const float* s = slab + (size_t)(((by * (by + 1)) >> 1) + b) * 512;
        z  += s[off];
        nv += s[128 + off];
    }
    int base = (b * (b + 1)) >> 1;       // j-side: blocks (bx, by=b)
    for (int bx = 0; bx <= b; ++bx) {
        const float* s = slab + (size_t)(base + bx) * 512;
        z  += s[256 + off];
        nv += s[384 + off];
    }
    __shared__ double sd[256];
    sd[threadIdx.x] = (double)nv / (double)z;
    __syncthreads();
    for (int st = 128; st > 0; st >>= 1) {
        if (threadIdx.x < st) sd[threadIdx.x] += sd[threadIdx.x + st];
        __syncthreads();
    }
    if (threadIdx.x == 0) {
        part[blockIdx.x] = sd[0];
        __threadfence();
        unsigned old = atomicAdd(cnt, 1u);
        if (old == 31u) {                // last block folds
            __threadfence();
            double a = 0.0;
            for (int k = 0; k < 32; ++k) a += part[k];
            out[0] = (float)(a / 67108864.0);   // / B^2
        }
    }
}

// ---------------- host launcher -----------------------------------------
extern "C" void kernel_launch(void* const* d_in, const int* in_sizes, int n_in,
                              void* d_out, int out_size, void* d_ws, size_t ws_size,
                              hipStream_t stream) {
    const float* V = (const float*)d_in[0];   // [8192, 512] f32
    const float* E = (const float*)d_in[1];   // [8192, 64]  f32
    float* out = (float*)d_out;
    char* ws = (char*)d_ws;

    float*         n_   = (float*)(ws + 0);            // 32 KB
    float*         ne   = (float*)(ws + 32768);        // 32 KB
    unsigned char* VF8  = (unsigned char*)(ws + 65536);// 4 MB fp8 V frags
    _Float16*      EFh  = (_Float16*)(ws + 4259840);   // 1 MB
    _Float16*      EFr  = (_Float16*)(ws + 5308416);   // 1 MB
    float*         slab = (float*)(ws + 6356992);      // 2080*512*4 = 4.26 MB
    double*        part = (double*)(ws + 10616832);    // 256 B
    unsigned*      cnt  = (unsigned*)(ws + 10617088);  // 4 B

    k_prep<<<512, 256, 0, stream>>>(V, E, n_, ne, VF8, EFh, EFr, cnt);
    k_mega<<<2080, 256, 0, stream>>>(VF8, EFh, EFr, ne, n_, slab);
    k_red <<<32, 256, 0, stream>>>(slab, part, cnt, out);
}

// Round 11
// 171.060 us; speedup vs baseline: 1.7007x; 1.1442x over previous
//
#include <hip/hip_runtime.h>

// TangentSpaceLoss: loss = (1/B^2) sum_ij softmax_j(E E^T)_ij * ||v_i - v_j||^2
// B=8192, G=512, D=64.
//
// R10 post-mortem: launch_bounds(256,4) (128-reg cap) + residual S-phase
// (peak live ~130+) => ~50 reg/thread spill (WRITE 4.2->110 MB). R11: drop
// the E residual — plain fp16 S (input-rounding-only error sigma(s)~5e-3,
// fp16 products are EXACT in fp32 accum; loss error <=~1.3e-10, budget
// 5.4e-10 with ref-side error 1.16e-10). Peak live ~112 < 128 -> no spill
// at 4 waves/SIMD. B h-frags hoisted (S loads 40->16/wave). Ballot-skip of
// exp/fma epilogue for all-unselected 16x16 tiles. EFr deleted.
//   G: fp8 e4m3 MFMA K=512 (VF8 frag-linear, 1KB wave-loads, no LDS/barriers)
//   S: fp16 MFMA (EFh frag-linear)
// Selection: s > min(ne_i,ne_j)-32 (safe superset; fp16 s err 0.025 << 32
// margin). Softmax shift ne_i; diagonal w=1, wd=0 -> +1.0 in k_red.
// XCD band swizzle; slab + k_red (R8-verified, atomic-free).
//
// VF8: [rt 512][c 8][m 16][q 4][kc 2][8B]; lane (m,quad) reads 16B at
// m*64+quad*16 (bytes 0-7 = K-chunk kc0, 8-15 = kc1).
// EFh: [rt 512][kc 2][m 16][k' 32] halfs.

#define SEL_T 32.0f

typedef _Float16 half8 __attribute__((ext_vector_type(8)));
typedef float    f32x4 __attribute__((ext_vector_type(4)));
typedef long     l2t   __attribute__((ext_vector_type(2)));

#define MFMA16(a, b, c) __builtin_amdgcn_mfma_f32_16x16x32_f16(a, b, c, 0, 0, 0)
#define MFMA8(a, b, c)  __builtin_amdgcn_mfma_f32_16x16x32_fp8_fp8(a, b, c, 0, 0, 0)

// ---------------- K1: norms + fp8 V + fp16 E layouts --------------------
__global__ __launch_bounds__(256) void k_prep(
    const float* __restrict__ V, const float* __restrict__ E,
    float* __restrict__ n, float* __restrict__ ne,
    unsigned char* __restrict__ VF8, _Float16* __restrict__ EFh,
    unsigned* __restrict__ cnt) {
    int rt = blockIdx.x;                       // 512 row-tiles of 16 rows
    int tid = threadIdx.x, wave = tid >> 6, lane = tid & 63;
    if (rt == 0 && tid == 0) *cnt = 0;
    int m = lane >> 2, q = lane & 3;
    int row = rt * 16 + m;
    const float* vr = V + (size_t)row * 512;
    float sn = 0.f;
#pragma unroll
    for (int it = 0; it < 2; ++it) {
        int c = wave + it * 4;                 // K-chunk of 64
        const float4* p0 = (const float4*)(vr + c * 64 + q * 8);
        const float4* p1 = (const float4*)(vr + c * 64 + 32 + q * 8);
        float4 a0 = p0[0], a1 = p0[1], b0 = p1[0], b1 = p1[1];
        int w0 = 0, w1 = 0, w2 = 0, w3 = 0;
        w0 = __builtin_amdgcn_cvt_pk_fp8_f32(a0.x, a0.y, w0, false);
        w0 = __builtin_amdgcn_cvt_pk_fp8_f32(a0.z, a0.w, w0, true);
        w1 = __builtin_amdgcn_cvt_pk_fp8_f32(a1.x, a1.y, w1, false);
        w1 = __builtin_amdgcn_cvt_pk_fp8_f32(a1.z, a1.w, w1, true);
        w2 = __builtin_amdgcn_cvt_pk_fp8_f32(b0.x, b0.y, w2, false);
        w2 = __builtin_amdgcn_cvt_pk_fp8_f32(b0.z, b0.w, w2, true);
        w3 = __builtin_amdgcn_cvt_pk_fp8_f32(b1.x, b1.y, w3, false);
        w3 = __builtin_amdgcn_cvt_pk_fp8_f32(b1.z, b1.w, w3, true);
        uint4 o;
        o.x = (unsigned)w0; o.y = (unsigned)w1;
        o.z = (unsigned)w2; o.w = (unsigned)w3;
        *(uint4*)(VF8 + (((size_t)rt * 8 + c) << 10) + lane * 16) = o;
        sn += a0.x*a0.x + a0.y*a0.y + a0.z*a0.z + a0.w*a0.w
            + a1.x*a1.x + a1.y*a1.y + a1.z*a1.z + a1.w*a1.w
            + b0.x*b0.x + b0.y*b0.y + b0.z*b0.z + b0.w*b0.w
            + b1.x*b1.x + b1.y*b1.y + b1.z*b1.z + b1.w*b1.w;
    }
    __shared__ float sred[4][64];
    sred[wave][lane] = sn;
    __syncthreads();
    if (tid < 16) {
        float s = 0.f;
#pragma unroll
        for (int w = 0; w < 4; ++w)
#pragma unroll
            for (int qq = 0; qq < 4; ++qq) s += sred[w][tid * 4 + qq];
        n[rt * 16 + tid] = s;
    }
    // E: threads 0..127: rl = t>>3, u = t&7, k in [u*8, u*8+8)
    if (tid < 128) {
        int rl = tid >> 3, u = tid & 7;
        int erow = rt * 16 + rl;
        const float4* er = (const float4*)(E + (size_t)erow * 64);
        float4 x0 = er[u * 2], x1 = er[u * 2 + 1];
        float xf[8] = {x0.x, x0.y, x0.z, x0.w, x1.x, x1.y, x1.z, x1.w};
        half8 h;
        float se = 0.f;
#pragma unroll
        for (int k = 0; k < 8; ++k) {
            h[k] = (_Float16)xf[k];
            se += xf[k] * xf[k];
        }
        int kc = u >> 2, qq = u & 3;
        *(half8*)(EFh + ((size_t)rt * 2 + kc) * 512 + rl * 32 + qq * 8) = h;
        se += __shfl_xor(se, 1, 64);
        se += __shfl_xor(se, 2, 64);
        se += __shfl_xor(se, 4, 64);
        if (u == 0) ne[erow] = se;
    }
}

// ---------------- K2: zero-LDS gather tile kernel -----------------------
// 256 thr = 4 waves in 2x2 grid; wave tile 64x64 = 4x4 MFMA tiles.
__global__ __launch_bounds__(256, 4) void k_mega(
    const unsigned char* __restrict__ VF8, const _Float16* __restrict__ EFh,
    const float* __restrict__ ne, const float* __restrict__ nrm,
    float* __restrict__ slab) {
    // XCD band swizzle + triangular decode: blk -> (bx <= by)
    int blk0 = blockIdx.x;
    int blk = (blk0 & 7) * 260 + (blk0 >> 3);
    int by = (int)((sqrtf(8.f * (float)blk + 1.f) - 1.f) * 0.5f);
    while ((by + 1) * (by + 2) / 2 <= blk) ++by;
    while (by * (by + 1) / 2 > blk) --by;
    int bx = blk - by * (by + 1) / 2;
    int i0 = bx << 7, j0 = by << 7;
    bool diag = (bx == by);
    float* myslab = slab + (size_t)blk * 512;

    __shared__ float sNeI[128], sNeJ[128], sNI[128], sNJ[128];
    __shared__ float scr[1024];

    int tid = threadIdx.x;
    if (tid < 128) { sNeI[tid] = ne[i0 + tid]; sNI[tid] = nrm[i0 + tid]; }
    else { sNeJ[tid - 128] = ne[j0 + tid - 128]; sNJ[tid - 128] = nrm[j0 + tid - 128]; }
    __syncthreads();

    int wave = tid >> 6, lane = tid & 63;
    int m = lane & 15, quad = lane >> 4;
    int wi = wave & 1, wj = wave >> 1;
    int rtA = (i0 >> 4) + wi * 4;            // + im
    int rtB = (j0 >> 4) + wj * 4;            // + jn
    size_t loH = (size_t)(m * 32 + quad * 8);   // halfs (E frags)
    size_t loB = (size_t)(m * 64 + quad * 16);  // bytes (V fp8 frags)

    // ---- G phase: K=512, 8 chunks of 64; fp8, no LDS, no barriers ----
    f32x4 gacc[4][4] = {};
    for (int c = 0; c < 8; ++c) {
        l2t a[4], b[4];
#pragma unroll
        for (int im = 0; im < 4; ++im)
            a[im] = *(const l2t*)(VF8 + (((size_t)(rtA + im) * 8 + c) << 10) + loB);
#pragma unroll
        for (int jn = 0; jn < 4; ++jn)
            b[jn] = *(const l2t*)(VF8 + (((size_t)(rtB + jn) * 8 + c) << 10) + loB);
#pragma unroll
        for (int jn = 0; jn < 4; ++jn)
#pragma unroll
            for (int im = 0; im < 4; ++im) {
                gacc[im][jn] = MFMA8(a[im][0], b[jn][0], gacc[im][jn]);
                gacc[im][jn] = MFMA8(a[im][1], b[jn][1], gacc[im][jn]);
            }
    }

    // ---- fused S phase + epilogue (plain fp16, B-frags hoisted) ----
    half8 bh[4][2];
#pragma unroll
    for (int jn = 0; jn < 4; ++jn) {
        size_t bb = (size_t)(rtB + jn) * 2 * 512 + loH;
        bh[jn][0] = *(const half8*)(EFh + bb);
        bh[jn][1] = *(const half8*)(EFh + bb + 512);
    }
    float zj[4] = {}, nj_[4] = {};
#pragma unroll
    for (int im = 0; im < 4; ++im) {
        size_t ab = (size_t)(rtA + im) * 2 * 512 + loH;
        half8 ah0 = *(const half8*)(EFh + ab);
        half8 ah1 = *(const half8*)(EFh + ab + 512);
        f32x4 zi4 = {0.f, 0.f, 0.f, 0.f};
        f32x4 ni4 = {0.f, 0.f, 0.f, 0.f};
#pragma unroll
        for (int jn = 0; jn < 4; ++jn) {
            f32x4 acc = {0.f, 0.f, 0.f, 0.f};
            acc = MFMA16(ah0, bh[jn][0], acc);
            acc = MFMA16(ah1, bh[jn][1], acc);
            int jl = (wj << 6) + jn * 16 + m;
            int jg = j0 + jl;
            float nej = sNeJ[jl], nnj = sNJ[jl];
            f32x4 g4 = gacc[im][jn];
            bool p[4];
            bool anyp = false;
#pragma unroll
            for (int r = 0; r < 4; ++r) {
                int il = (wi << 6) + im * 16 + quad * 4 + r;
                int ig = i0 + il;
                float nei = sNeI[il];
                p[r] = (acc[r] > fminf(nei, nej) - SEL_T) && (!diag || ig < jg);
                anyp |= p[r];
            }
            if (__builtin_amdgcn_ballot_w64(anyp)) {   // wave-uniform skip
#pragma unroll
                for (int r = 0; r < 4; ++r) {
                    if (p[r]) {
                        int il = (wi << 6) + im * 16 + quad * 4 + r;
                        float nei = sNeI[il], nni = sNI[il];
                        float s = acc[r];
                        float wiw = __expf(s - nei);
                        float wjw = __expf(s - nej);
                        float wd = nni + nnj - 2.f * g4[r];
                        zi4[r] += wiw;  ni4[r] += wiw * wd;
                        zj[jn] += wjw;  nj_[jn] += wjw * wd;
                    }
                }
            }
        }
        // i-side: reduce over 16 m-lanes, write wj-plane
#pragma unroll
        for (int msk = 1; msk < 16; msk <<= 1) {
#pragma unroll
            for (int r = 0; r < 4; ++r) {
                zi4[r] += __shfl_xor(zi4[r], msk, 64);
                ni4[r] += __shfl_xor(ni4[r], msk, 64);
            }
        }
        if (m == 0) {
            int row0 = (wi << 6) + im * 16 + quad * 4;
            *(f32x4*)(scr + (wj << 7) + row0)       = zi4;
            *(f32x4*)(scr + 256 + (wj << 7) + row0) = ni4;
        }
    }
    // j-side: reduce over quads, write wi-plane
#pragma unroll
    for (int msk = 16; msk < 64; msk <<= 1) {
#pragma unroll
        for (int jn = 0; jn < 4; ++jn) {
            zj[jn]  += __shfl_xor(zj[jn],  msk, 64);
            nj_[jn] += __shfl_xor(nj_[jn], msk, 64);
        }
    }
    if (quad == 0) {
#pragma unroll
        for (int jn = 0; jn < 4; ++jn) {
            int jl = (wj << 6) + jn * 16 + m;
            scr[512 + (wi << 7) + jl] = zj[jn];
            scr[768 + (wi << 7) + jl] = nj_[jn];
        }
    }
    __syncthreads();
    // fold planes -> exclusive coalesced slab stores
    if (tid < 128) {
        myslab[tid]       = scr[tid]       + scr[128 + tid];
        myslab[128 + tid] = scr[256 + tid] + scr[384 + tid];
    } else {
        int cidx = tid - 128;
        myslab[256 + cidx] = scr[512 + cidx] + scr[640 + cidx];
        myslab[384 + cidx] = scr[768 + cidx] + scr[896 + cidx];
    }
}

// ------- K3: slab fold + reduce + last-block final (one launch) ---------
__global__ __launch_bounds__(256) void k_red(
    const float* __restrict__ slab, double* __restrict__ part,
    unsigned* __restrict__ cnt, float* __restrict__ out) {
    int r = (blockIdx.x << 8) + threadIdx.x;
    int b = r >> 7, off = r & 127;
    float z = 1.0f, nv = 0.0f;           // +1: diagonal w=1, wd=0
    for (int by = b; by < 64; ++by) {    // i-side: blocks (bx=b, by)
        const float* s = slab + (size_t)(((by * (by + 1)) >> 1) + b) * 512;
        z  += s[off];
        nv += s[128 + off];
    }
    int base = (b * (b + 1)) >> 1;       // j-side: blocks (bx, by=b)
    for (int bx = 0; bx <= b; ++bx) {
        const float* s = slab + (size_t)(base + bx) * 512;
        z  += s[256 + off];
        nv += s[384 + off];
    }
    __shared__ double sd[256];
    sd[threadIdx.x] = (double)nv / (double)z;
    __syncthreads();
    for (int st = 128; st > 0; st >>= 1) {
        if (threadIdx.x < st) sd[threadIdx.x] += sd[threadIdx.x + st];
        __syncthreads();
    }
    if (threadIdx.x == 0) {
        part[blockIdx.x] = sd[0];
        __threadfence();
        unsigned old = atomicAdd(cnt, 1u);
        if (old == 31u) {                // last block folds
            __threadfence();
            double a = 0.0;
            for (int k = 0; k < 32; ++k) a += part[k];
            out[0] = (float)(a / 67108864.0);   // / B^2
        }
    }
}

// ---------------- host launcher -----------------------------------------
extern "C" void kernel_launch(void* const* d_in, const int* in_sizes, int n_in,
                              void* d_out, int out_size, void* d_ws, size_t ws_size,
                              hipStream_t stream) {
    const float* V = (const float*)d_in[0];   // [8192, 512] f32
    const float* E = (const float*)d_in[1];   // [8192, 64]  f32
    float* out = (float*)d_out;
    char* ws = (char*)d_ws;

    float*         n_   = (float*)(ws + 0);            // 32 KB
    float*         ne   = (float*)(ws + 32768);        // 32 KB
    unsigned char* VF8  = (unsigned char*)(ws + 65536);// 4 MB fp8 V frags
    _Float16*      EFh  = (_Float16*)(ws + 4259840);   // 1 MB
    float*         slab = (float*)(ws + 5308416);      // 2080*512*4 = 4.26 MB
    double*        part = (double*)(ws + 9568256);     // 256 B
    unsigned*      cnt  = (unsigned*)(ws + 9568512);   // 4 B

    k_prep<<<512, 256, 0, stream>>>(V, E, n_, ne, VF8, EFh, cnt);
    k_mega<<<2080, 256, 0, stream>>>(VF8, EFh, ne, n_, slab);
    k_red <<<32, 256, 0, stream>>>(slab, part, cnt, out);
}

// Round 12
// 150.706 us; speedup vs baseline: 1.9304x; 1.1351x over previous
//
#include <hip/hip_runtime.h>

// TangentSpaceLoss: loss = (1/B^2) sum_ij softmax_j(E E^T)_ij * ||v_i - v_j||^2
// B=8192, G=512, D=64.
//
// R11 post-mortem: (256,4) => compiler split 128 regs as 64 VGPR + 64 AGPR
// (gacc); epilogue VGPR set (~60) spills ~50B/thread -> WRITE 112 MB, kernel
// latency-bound on the scratch round-trip. R12: (256,3) -> 170-reg cap fits
// everything (gacc 64 AGPR + ~60 VGPR) with NO spill; 12 waves/CU. k_red
// widened to 64 blocks x 128 thr. All else unchanged from R11:
//   G: fp8 e4m3 MFMA K=512 (VF8 frag-linear, 16B/lane wave-loads, no LDS,
//      no barriers in the loop)   S: fp16 MFMA (EFh frag-linear, B hoisted)
//   fused epilogue w/ ballot-skip; LDS-plane combine; slab (atomic-free);
//   k_red last-block final fold.
// Selection: s > min(ne_i,ne_j)-32 (safe superset). Softmax shift ne_i;
// diagonal w=1, wd=0 -> +1.0 in k_red. XCD band swizzle (2080 = 8*260).
//
// VF8: [rt 512][c 8][m 16][q 4][kc 2][8B]; lane (m,quad) reads 16B at
// m*64+quad*16 (bytes 0-7 = K-chunk kc0, 8-15 = kc1).
// EFh: [rt 512][kc 2][m 16][k' 32] halfs.

#define SEL_T 32.0f

typedef _Float16 half8 __attribute__((ext_vector_type(8)));
typedef float    f32x4 __attribute__((ext_vector_type(4)));
typedef long     l2t   __attribute__((ext_vector_type(2)));

#define MFMA16(a, b, c) __builtin_amdgcn_mfma_f32_16x16x32_f16(a, b, c, 0, 0, 0)
#define MFMA8(a, b, c)  __builtin_amdgcn_mfma_f32_16x16x32_fp8_fp8(a, b, c, 0, 0, 0)

// ---------------- K1: norms + fp8 V + fp16 E layouts --------------------
__global__ __launch_bounds__(256) void k_prep(
    const float* __restrict__ V, const float* __restrict__ E,
    float* __restrict__ n, float* __restrict__ ne,
    unsigned char* __restrict__ VF8, _Float16* __restrict__ EFh,
    unsigned* __restrict__ cnt) {
    int rt = blockIdx.x;                       // 512 row-tiles of 16 rows
    int tid = threadIdx.x, wave = tid >> 6, lane = tid & 63;
    if (rt == 0 && tid == 0) *cnt = 0;
    int m = lane >> 2, q = lane & 3;
    int row = rt * 16 + m;
    const float* vr = V + (size_t)row * 512;
    float sn = 0.f;
#pragma unroll
    for (int it = 0; it < 2; ++it) {
        int c = wave + it * 4;                 // K-chunk of 64
        const float4* p0 = (const float4*)(vr + c * 64 + q * 8);
        const float4* p1 = (const float4*)(vr + c * 64 + 32 + q * 8);
        float4 a0 = p0[0], a1 = p0[1], b0 = p1[0], b1 = p1[1];
        int w0 = 0, w1 = 0, w2 = 0, w3 = 0;
        w0 = __builtin_amdgcn_cvt_pk_fp8_f32(a0.x, a0.y, w0, false);
        w0 = __builtin_amdgcn_cvt_pk_fp8_f32(a0.z, a0.w, w0, true);
        w1 = __builtin_amdgcn_cvt_pk_fp8_f32(a1.x, a1.y, w1, false);
        w1 = __builtin_amdgcn_cvt_pk_fp8_f32(a1.z, a1.w, w1, true);
        w2 = __builtin_amdgcn_cvt_pk_fp8_f32(b0.x, b0.y, w2, false);
        w2 = __builtin_amdgcn_cvt_pk_fp8_f32(b0.z, b0.w, w2, true);
        w3 = __builtin_amdgcn_cvt_pk_fp8_f32(b1.x, b1.y, w3, false);
        w3 = __builtin_amdgcn_cvt_pk_fp8_f32(b1.z, b1.w, w3, true);
        uint4 o;
        o.x = (unsigned)w0; o.y = (unsigned)w1;
        o.z = (unsigned)w2; o.w = (unsigned)w3;
        *(uint4*)(VF8 + (((size_t)rt * 8 + c) << 10) + lane * 16) = o;
        sn += a0.x*a0.x + a0.y*a0.y + a0.z*a0.z + a0.w*a0.w
            + a1.x*a1.x + a1.y*a1.y + a1.z*a1.z + a1.w*a1.w
            + b0.x*b0.x + b0.y*b0.y + b0.z*b0.z + b0.w*b0.w
            + b1.x*b1.x + b1.y*b1.y + b1.z*b1.z + b1.w*b1.w;
    }
    __shared__ float sred[4][64];
    sred[wave][lane] = sn;
    __syncthreads();
    if (tid < 16) {
        float s = 0.f;
#pragma unroll
        for (int w = 0; w < 4; ++w)
#pragma unroll
            for (int qq = 0; qq < 4; ++qq) s += sred[w][tid * 4 + qq];
        n[rt * 16 + tid] = s;
    }
    // E: threads 0..127: rl = t>>3, u = t&7, k in [u*8, u*8+8)
    if (tid < 128) {
        int rl = tid >> 3, u = tid & 7;
        int erow = rt * 16 + rl;
        const float4* er = (const float4*)(E + (size_t)erow * 64);
        float4 x0 = er[u * 2], x1 = er[u * 2 + 1];
        float xf[8] = {x0.x, x0.y, x0.z, x0.w, x1.x, x1.y, x1.z, x1.w};
        half8 h;
        float se = 0.f;
#pragma unroll
        for (int k = 0; k < 8; ++k) {
            h[k] = (_Float16)xf[k];
            se += xf[k] * xf[k];
        }
        int kc = u >> 2, qq = u & 3;
        *(half8*)(EFh + ((size_t)rt * 2 + kc) * 512 + rl * 32 + qq * 8) = h;
        se += __shfl_xor(se, 1, 64);
        se += __shfl_xor(se, 2, 64);
        se += __shfl_xor(se, 4, 64);
        if (u == 0) ne[erow] = se;
    }
}

// ---------------- K2: zero-LDS gather tile kernel -----------------------
// 256 thr = 4 waves in 2x2 grid; wave tile 64x64 = 4x4 MFMA tiles.
__global__ __launch_bounds__(256, 3) void k_mega(
    const unsigned char* __restrict__ VF8, const _Float16* __restrict__ EFh,
    const float* __restrict__ ne, const float* __restrict__ nrm,
    float* __restrict__ slab) {
    // XCD band swizzle + triangular decode: blk -> (bx <= by)
    int blk0 = blockIdx.x;
    int blk = (blk0 & 7) * 260 + (blk0 >> 3);
    int by = (int)((sqrtf(8.f * (float)blk + 1.f) - 1.f) * 0.5f);
    while ((by + 1) * (by + 2) / 2 <= blk) ++by;
    while (by * (by + 1) / 2 > blk) --by;
    int bx = blk - by * (by + 1) / 2;
    int i0 = bx << 7, j0 = by << 7;
    bool diag = (bx == by);
    float* myslab = slab + (size_t)blk * 512;

    __shared__ float sNeI[128], sNeJ[128], sNI[128], sNJ[128];
    __shared__ float scr[1024];

    int tid = threadIdx.x;
    if (tid < 128) { sNeI[tid] = ne[i0 + tid]; sNI[tid] = nrm[i0 + tid]; }
    else { sNeJ[tid - 128] = ne[j0 + tid - 128]; sNJ[tid - 128] = nrm[j0 + tid - 128]; }
    __syncthreads();

    int wave = tid >> 6, lane = tid & 63;
    int m = lane & 15, quad = lane >> 4;
    int wi = wave & 1, wj = wave >> 1;
    int rtA = (i0 >> 4) + wi * 4;            // + im
    int rtB = (j0 >> 4) + wj * 4;            // + jn
    size_t loH = (size_t)(m * 32 + quad * 8);   // halfs (E frags)
    size_t loB = (size_t)(m * 64 + quad * 16);  // bytes (V fp8 frags)

    // ---- G phase: K=512, 8 chunks of 64; fp8, no LDS, no barriers ----
    f32x4 gacc[4][4] = {};
    for (int c = 0; c < 8; ++c) {
        l2t a[4], b[4];
#pragma unroll
        for (int im = 0; im < 4; ++im)
            a[im] = *(const l2t*)(VF8 + (((size_t)(rtA + im) * 8 + c) << 10) + loB);
#pragma unroll
        for (int jn = 0; jn < 4; ++jn)
            b[jn] = *(const l2t*)(VF8 + (((size_t)(rtB + jn) * 8 + c) << 10) + loB);
#pragma unroll
        for (int jn = 0; jn < 4; ++jn)
#pragma unroll
            for (int im = 0; im < 4; ++im) {
                gacc[im][jn] = MFMA8(a[im][0], b[jn][0], gacc[im][jn]);
                gacc[im][jn] = MFMA8(a[im][1], b[jn][1], gacc[im][jn]);
            }
    }

    // ---- fused S phase + epilogue (plain fp16, B-frags hoisted) ----
    half8 bh[4][2];
#pragma unroll
    for (int jn = 0; jn < 4; ++jn) {
        size_t bb = (size_t)(rtB + jn) * 2 * 512 + loH;
        bh[jn][0] = *(const half8*)(EFh + bb);
        bh[jn][1] = *(const half8*)(EFh + bb + 512);
    }
    float zj[4] = {}, nj_[4] = {};
#pragma unroll
    for (int im = 0; im < 4; ++im) {
        size_t ab = (size_t)(rtA + im) * 2 * 512 + loH;
        half8 ah0 = *(const half8*)(EFh + ab);
        half8 ah1 = *(const half8*)(EFh + ab + 512);
        f32x4 zi4 = {0.f, 0.f, 0.f, 0.f};
        f32x4 ni4 = {0.f, 0.f, 0.f, 0.f};
#pragma unroll
        for (int jn = 0; jn < 4; ++jn) {
            f32x4 acc = {0.f, 0.f, 0.f, 0.f};
            acc = MFMA16(ah0, bh[jn][0], acc);
            acc = MFMA16(ah1, bh[jn][1], acc);
            int jl = (wj << 6) + jn * 16 + m;
            int jg = j0 + jl;
            float nej = sNeJ[jl], nnj = sNJ[jl];
            f32x4 g4 = gacc[im][jn];
            bool p[4];
            bool anyp = false;
#pragma unroll
            for (int r = 0; r < 4; ++r) {
                int il = (wi << 6) + im * 16 + quad * 4 + r;
                int ig = i0 + il;
                float nei = sNeI[il];
                p[r] = (acc[r] > fminf(nei, nej) - SEL_T) && (!diag || ig < jg);
                anyp |= p[r];
            }
            if (__builtin_amdgcn_ballot_w64(anyp)) {   // wave-uniform skip
#pragma unroll
                for (int r = 0; r < 4; ++r) {
                    if (p[r]) {
                        int il = (wi << 6) + im * 16 + quad * 4 + r;
                        float nei = sNeI[il], nni = sNI[il];
                        float s = acc[r];
                        float wiw = __expf(s - nei);
                        float wjw = __expf(s - nej);
                        float wd = nni + nnj - 2.f * g4[r];
                        zi4[r] += wiw;  ni4[r] += wiw * wd;
                        zj[jn] += wjw;  nj_[jn] += wjw * wd;
                    }
                }
            }
        }
        // i-side: reduce over 16 m-lanes, write wj-plane
#pragma unroll
        for (int msk = 1; msk < 16; msk <<= 1) {
#pragma unroll
            for (int r = 0; r < 4; ++r) {
                zi4[r] += __shfl_xor(zi4[r], msk, 64);
                ni4[r] += __shfl_xor(ni4[r], msk, 64);
            }
        }
        if (m == 0) {
            int row0 = (wi << 6) + im * 16 + quad * 4;
            *(f32x4*)(scr + (wj << 7) + row0)       = zi4;
            *(f32x4*)(scr + 256 + (wj << 7) + row0) = ni4;
        }
    }
    // j-side: reduce over quads, write wi-plane
#pragma unroll
    for (int msk = 16; msk < 64; msk <<= 1) {
#pragma unroll
        for (int jn = 0; jn < 4; ++jn) {
            zj[jn]  += __shfl_xor(zj[jn],  msk, 64);
            nj_[jn] += __shfl_xor(nj_[jn], msk, 64);
        }
    }
    if (quad == 0) {
#pragma unroll
        for (int jn = 0; jn < 4; ++jn) {
            int jl = (wj << 6) + jn * 16 + m;
            scr[512 + (wi << 7) + jl] = zj[jn];
            scr[768 + (wi << 7) + jl] = nj_[jn];
        }
    }
    __syncthreads();
    // fold planes -> exclusive coalesced slab stores
    if (tid < 128) {
        myslab[tid]       = scr[tid]       + scr[128 + tid];
        myslab[128 + tid] = scr[256 + tid] + scr[384 + tid];
    } else {
        int cidx = tid - 128;
        myslab[256 + cidx] = scr[512 + cidx] + scr[640 + cidx];
        myslab[384 + cidx] = scr[768 + cidx] + scr[896 + cidx];
    }
}

// ------- K3: slab fold + reduce + last-block final (one launch) ---------
__global__ __launch_bounds__(128) void k_red(
    const float* __restrict__ slab, double* __restrict__ part,
    unsigned* __restrict__ cnt, float* __restrict__ out) {
    int r = (blockIdx.x << 7) + threadIdx.x;   // 64 blocks x 128 threads
    int b = r >> 7, off = r & 127;
    float z = 1.0f, nv = 0.0f;           // +1: diagonal w=1, wd=0
    for (int by = b; by < 64; ++by) {    // i-side: blocks (bx=b, by)
        const float* s = slab + (size_t)(((by * (by + 1)) >> 1) + b) * 512;
        z  += s[off];
        nv += s[128 + off];
    }
    int base = (b * (b + 1)) >> 1;       // j-side: blocks (bx, by=b)
    for (int bx = 0; bx <= b; ++bx) {
        const float* s = slab + (size_t)(base + bx) * 512;
        z  += s[256 + off];
        nv += s[384 + off];
    }
    __shared__ double sd[128];
    sd[threadIdx.x] = (double)nv / (double)z;
    __syncthreads();
    for (int st = 64; st > 0; st >>= 1) {
        if (threadIdx.x < st) sd[threadIdx.x] += sd[threadIdx.x + st];
        __syncthreads();
    }
    if (threadIdx.x == 0) {
        part[blockIdx.x] = sd[0];
        __threadfence();
        unsigned old = atomicAdd(cnt, 1u);
        if (old == 63u) {                // last block folds
            __threadfence();
            double a = 0.0;
            for (int k = 0; k < 64; ++k) a += part[k];
            out[0] = (float)(a / 67108864.0);   // / B^2
        }
    }
}

// ---------------- host launcher -----------------------------------------
extern "C" void kernel_launch(void* const* d_in, const int* in_sizes, int n_in,
                              void* d_out, int out_size, void* d_ws, size_t ws_size,
                              hipStream_t stream) {
    const float* V = (const float*)d_in[0];   // [8192, 512] f32
    const float* E = (const float*)d_in[1];   // [8192, 64]  f32
    float* out = (float*)d_out;
    char* ws = (char*)d_ws;

    float*         n_   = (float*)(ws + 0);            // 32 KB
    float*         ne   = (float*)(ws + 32768);        // 32 KB
    unsigned char* VF8  = (unsigned char*)(ws + 65536);// 4 MB fp8 V frags
    _Float16*      EFh  = (_Float16*)(ws + 4259840);   // 1 MB
    float*         slab = (float*)(ws + 5308416);      // 2080*512*4 = 4.26 MB
    double*        part = (double*)(ws + 9568256);     // 512 B
    unsigned*      cnt  = (unsigned*)(ws + 9568768);   // 4 B

    k_prep<<<512, 256, 0, stream>>>(V, E, n_, ne, VF8, EFh, cnt);
    k_mega<<<2080, 256, 0, stream>>>(VF8, EFh, ne, n_, slab);
    k_red <<<64, 128, 0, stream>>>(slab, part, cnt, out);
}

// Round 13
// 135.060 us; speedup vs baseline: 2.1540x; 1.1158x over previous
//
#include <hip/hip_runtime.h>

// TangentSpaceLoss: loss = (1/B^2) sum_ij softmax_j(E E^T)_ij * ||v_i - v_j||^2
// B=8192, G=512, D=64.
//
// R12 post-mortem: k_mega 68us (no spill, all pipes <30%); the tail is the
// slab fold: k_red = 64 blocks x 130 scattered slab-gathers (~30-40us of the
// constant ~83us non-mega time). R13: slab DELETED — epilogue does direct
// atomicAdd into 64KB L2-resident Z/num (atomics were exonerated in R8: the
// phantom WRITE traffic followed the LDS-staging structure, gone since R9).
// 512 spread atomics/block, zero-skip for empty rows. Z=1/num=0 init in
// k_prep. k_red = trivial 8192-row num/Z reduce + last-block final fold
// (kernel boundary guarantees cross-XCD visibility of device-scope atomics).
//   G: fp8 e4m3 MFMA K=512 (VF8 frag-linear, 16B/lane wave-loads, no LDS
//      staging, no barriers in the loop)
//   S: fp16 MFMA (EFh frag-linear, B-frags hoisted), fused epilogue with
//      ballot-skip; LDS-plane cross-wave combine (R8-verified).
// Selection: s > min(ne_i,ne_j)-32 (safe superset). Softmax shift ne_i;
// diagonal w=1, wd=0 -> Z preinit 1. XCD band swizzle (2080 = 8*260).
// k_mega at __launch_bounds__(256,3): gacc(64 AGPR)+~84 VGPR fits, no spill
// (R12-verified; (256,4) spills ~50B/thread).
//
// VF8: [rt 512][c 8][m 16][q 4][kc 2][8B]; lane (m,quad) reads 16B at
// m*64+quad*16 (bytes 0-7 = K-chunk kc0, 8-15 = kc1).
// EFh: [rt 512][kc 2][m 16][k' 32] halfs.

#define SEL_T 32.0f

typedef _Float16 half8 __attribute__((ext_vector_type(8)));
typedef float    f32x4 __attribute__((ext_vector_type(4)));
typedef long     l2t   __attribute__((ext_vector_type(2)));

#define MFMA16(a, b, c) __builtin_amdgcn_mfma_f32_16x16x32_f16(a, b, c, 0, 0, 0)
#define MFMA8(a, b, c)  __builtin_amdgcn_mfma_f32_16x16x32_fp8_fp8(a, b, c, 0, 0, 0)

// ---------------- K1: norms + fp8 V + fp16 E layouts + Z/num init -------
__global__ __launch_bounds__(256) void k_prep(
    const float* __restrict__ V, const float* __restrict__ E,
    float* __restrict__ n, float* __restrict__ ne,
    float* __restrict__ Z, float* __restrict__ num,
    unsigned char* __restrict__ VF8, _Float16* __restrict__ EFh,
    unsigned* __restrict__ cnt) {
    int rt = blockIdx.x;                       // 512 row-tiles of 16 rows
    int tid = threadIdx.x, wave = tid >> 6, lane = tid & 63;
    if (rt == 0 && tid == 0) *cnt = 0;
    int m = lane >> 2, q = lane & 3;
    int row = rt * 16 + m;
    const float* vr = V + (size_t)row * 512;
    float sn = 0.f;
#pragma unroll
    for (int it = 0; it < 2; ++it) {
        int c = wave + it * 4;                 // K-chunk of 64
        const float4* p0 = (const float4*)(vr + c * 64 + q * 8);
        const float4* p1 = (const float4*)(vr + c * 64 + 32 + q * 8);
        float4 a0 = p0[0], a1 = p0[1], b0 = p1[0], b1 = p1[1];
        int w0 = 0, w1 = 0, w2 = 0, w3 = 0;
        w0 = __builtin_amdgcn_cvt_pk_fp8_f32(a0.x, a0.y, w0, false);
        w0 = __builtin_amdgcn_cvt_pk_fp8_f32(a0.z, a0.w, w0, true);
        w1 = __builtin_amdgcn_cvt_pk_fp8_f32(a1.x, a1.y, w1, false);
        w1 = __builtin_amdgcn_cvt_pk_fp8_f32(a1.z, a1.w, w1, true);
        w2 = __builtin_amdgcn_cvt_pk_fp8_f32(b0.x, b0.y, w2, false);
        w2 = __builtin_amdgcn_cvt_pk_fp8_f32(b0.z, b0.w, w2, true);
        w3 = __builtin_amdgcn_cvt_pk_fp8_f32(b1.x, b1.y, w3, false);
        w3 = __builtin_amdgcn_cvt_pk_fp8_f32(b1.z, b1.w, w3, true);
        uint4 o;
        o.x = (unsigned)w0; o.y = (unsigned)w1;
        o.z = (unsigned)w2; o.w = (unsigned)w3;
        *(uint4*)(VF8 + (((size_t)rt * 8 + c) << 10) + lane * 16) = o;
        sn += a0.x*a0.x + a0.y*a0.y + a0.z*a0.z + a0.w*a0.w
            + a1.x*a1.x + a1.y*a1.y + a1.z*a1.z + a1.w*a1.w
            + b0.x*b0.x + b0.y*b0.y + b0.z*b0.z + b0.w*b0.w
            + b1.x*b1.x + b1.y*b1.y + b1.z*b1.z + b1.w*b1.w;
    }
    __shared__ float sred[4][64];
    sred[wave][lane] = sn;
    __syncthreads();
    if (tid < 16) {
        float s = 0.f;
#pragma unroll
        for (int w = 0; w < 4; ++w)
#pragma unroll
            for (int qq = 0; qq < 4; ++qq) s += sred[w][tid * 4 + qq];
        int rr = rt * 16 + tid;
        n[rr] = s;
        Z[rr] = 1.0f;                          // diagonal w=1, wd=0
        num[rr] = 0.0f;
    }
    // E: threads 0..127: rl = t>>3, u = t&7, k in [u*8, u*8+8)
    if (tid < 128) {
        int rl = tid >> 3, u = tid & 7;
        int erow = rt * 16 + rl;
        const float4* er = (const float4*)(E + (size_t)erow * 64);
        float4 x0 = er[u * 2], x1 = er[u * 2 + 1];
        float xf[8] = {x0.x, x0.y, x0.z, x0.w, x1.x, x1.y, x1.z, x1.w};
        half8 h;
        float se = 0.f;
#pragma unroll
        for (int k = 0; k < 8; ++k) {
            h[k] = (_Float16)xf[k];
            se += xf[k] * xf[k];
        }
        int kc = u >> 2, qq = u & 3;
        *(half8*)(EFh + ((size_t)rt * 2 + kc) * 512 + rl * 32 + qq * 8) = h;
        se += __shfl_xor(se, 1, 64);
        se += __shfl_xor(se, 2, 64);
        se += __shfl_xor(se, 4, 64);
        if (u == 0) ne[erow] = se;
    }
}

// ---------------- K2: zero-LDS gather tile kernel -----------------------
// 256 thr = 4 waves in 2x2 grid; wave tile 64x64 = 4x4 MFMA tiles.
__global__ __launch_bounds__(256, 3) void k_mega(
    const unsigned char* __restrict__ VF8, const _Float16* __restrict__ EFh,
    const float* __restrict__ ne, const float* __restrict__ nrm,
    float* __restrict__ Z, float* __restrict__ num) {
    // XCD band swizzle + triangular decode: blk -> (bx <= by)
    int blk0 = blockIdx.x;
    int blk = (blk0 & 7) * 260 + (blk0 >> 3);
    int by = (int)((sqrtf(8.f * (float)blk + 1.f) - 1.f) * 0.5f);
    while ((by + 1) * (by + 2) / 2 <= blk) ++by;
    while (by * (by + 1) / 2 > blk) --by;
    int bx = blk - by * (by + 1) / 2;
    int i0 = bx << 7, j0 = by << 7;
    bool diag = (bx == by);

    __shared__ float sNeI[128], sNeJ[128], sNI[128], sNJ[128];
    __shared__ float scr[1024];

    int tid = threadIdx.x;
    if (tid < 128) { sNeI[tid] = ne[i0 + tid]; sNI[tid] = nrm[i0 + tid]; }
    else { sNeJ[tid - 128] = ne[j0 + tid - 128]; sNJ[tid - 128] = nrm[j0 + tid - 128]; }
    __syncthreads();

    int wave = tid >> 6, lane = tid & 63;
    int m = lane & 15, quad = lane >> 4;
    int wi = wave & 1, wj = wave >> 1;
    int rtA = (i0 >> 4) + wi * 4;            // + im
    int rtB = (j0 >> 4) + wj * 4;            // + jn
    size_t loH = (size_t)(m * 32 + quad * 8);   // halfs (E frags)
    size_t loB = (size_t)(m * 64 + quad * 16);  // bytes (V fp8 frags)

    // ---- G phase: K=512, 8 chunks of 64; fp8, no LDS, no barriers ----
    f32x4 gacc[4][4] = {};
    for (int c = 0; c < 8; ++c) {
        l2t a[4], b[4];
#pragma unroll
        for (int im = 0; im < 4; ++im)
            a[im] = *(const l2t*)(VF8 + (((size_t)(rtA + im) * 8 + c) << 10) + loB);
#pragma unroll
        for (int jn = 0; jn < 4; ++jn)
            b[jn] = *(const l2t*)(VF8 + (((size_t)(rtB + jn) * 8 + c) << 10) + loB);
#pragma unroll
        for (int jn = 0; jn < 4; ++jn)
#pragma unroll
            for (int im = 0; im < 4; ++im) {
                gacc[im][jn] = MFMA8(a[im][0], b[jn][0], gacc[im][jn]);
                gacc[im][jn] = MFMA8(a[im][1], b[jn][1], gacc[im][jn]);
            }
    }

    // ---- fused S phase + epilogue (plain fp16, B-frags hoisted) ----
    half8 bh[4][2];
#pragma unroll
    for (int jn = 0; jn < 4; ++jn) {
        size_t bb = (size_t)(rtB + jn) * 2 * 512 + loH;
        bh[jn][0] = *(const half8*)(EFh + bb);
        bh[jn][1] = *(const half8*)(EFh + bb + 512);
    }
    float zj[4] = {}, nj_[4] = {};
#pragma unroll
    for (int im = 0; im < 4; ++im) {
        size_t ab = (size_t)(rtA + im) * 2 * 512 + loH;
        half8 ah0 = *(const half8*)(EFh + ab);
        half8 ah1 = *(const half8*)(EFh + ab + 512);
        f32x4 zi4 = {0.f, 0.f, 0.f, 0.f};
        f32x4 ni4 = {0.f, 0.f, 0.f, 0.f};
#pragma unroll
        for (int jn = 0; jn < 4; ++jn) {
            f32x4 acc = {0.f, 0.f, 0.f, 0.f};
            acc = MFMA16(ah0, bh[jn][0], acc);
            acc = MFMA16(ah1, bh[jn][1], acc);
            int jl = (wj << 6) + jn * 16 + m;
            int jg = j0 + jl;
            float nej = sNeJ[jl], nnj = sNJ[jl];
            f32x4 g4 = gacc[im][jn];
            bool p[4];
            bool anyp = false;
#pragma unroll
            for (int r = 0; r < 4; ++r) {
                int il = (wi << 6) + im * 16 + quad * 4 + r;
                int ig = i0 + il;
                float nei = sNeI[il];
                p[r] = (acc[r] > fminf(nei, nej) - SEL_T) && (!diag || ig < jg);
                anyp |= p[r];
            }
            if (__builtin_amdgcn_ballot_w64(anyp)) {   // wave-uniform skip
#pragma unroll
                for (int r = 0; r < 4; ++r) {
                    if (p[r]) {
                        int il = (wi << 6) + im * 16 + quad * 4 + r;
                        float nei = sNeI[il], nni = sNI[il];
                        float s = acc[r];
                        float wiw = __expf(s - nei);
                        float wjw = __expf(s - nej);
                        float wd = nni + nnj - 2.f * g4[r];
                        zi4[r] += wiw;  ni4[r] += wiw * wd;
                        zj[jn] += wjw;  nj_[jn] += wjw * wd;
                    }
                }
            }
        }
        // i-side: reduce over 16 m-lanes, write wj-plane
#pragma unroll
        for (int msk = 1; msk < 16; msk <<= 1) {
#pragma unroll
            for (int r = 0; r < 4; ++r) {
                zi4[r] += __shfl_xor(zi4[r], msk, 64);
                ni4[r] += __shfl_xor(ni4[r], msk, 64);
            }
        }
        if (m == 0) {
            int row0 = (wi << 6) + im * 16 + quad * 4;
            *(f32x4*)(scr + (wj << 7) + row0)       = zi4;
            *(f32x4*)(scr + 256 + (wj << 7) + row0) = ni4;
        }
    }
    // j-side: reduce over quads, write wi-plane
#pragma unroll
    for (int msk = 16; msk < 64; msk <<= 1) {
#pragma unroll
        for (int jn = 0; jn < 4; ++jn) {
            zj[jn]  += __shfl_xor(zj[jn],  msk, 64);
            nj_[jn] += __shfl_xor(nj_[jn], msk, 64);
        }
    }
    if (quad == 0) {
#pragma unroll
        for (int jn = 0; jn < 4; ++jn) {
            int jl = (wj << 6) + jn * 16 + m;
            scr[512 + (wi << 7) + jl] = zj[jn];
            scr[768 + (wi << 7) + jl] = nj_[jn];
        }
    }
    __syncthreads();
    // fold planes -> direct device atomics (zero-skip for empty rows)
    if (tid < 128) {
        float az = scr[tid]       + scr[128 + tid];
        float an = scr[256 + tid] + scr[384 + tid];
        if (az != 0.f || an != 0.f) {
            atomicAdd(Z + i0 + tid,   az);
            atomicAdd(num + i0 + tid, an);
        }
    } else {
        int cidx = tid - 128;
        float az = scr[512 + cidx] + scr[640 + cidx];
        float an = scr[768 + cidx] + scr[896 + cidx];
        if (az != 0.f || an != 0.f) {
            atomicAdd(Z + j0 + cidx,   az);
            atomicAdd(num + j0 + cidx, an);
        }
    }
}

// ------- K3: trivial 8192-row reduce + last-block final fold ------------
__global__ __launch_bounds__(256) void k_red(
    const float* __restrict__ Z, const float* __restrict__ num,
    double* __restrict__ part, unsigned* __restrict__ cnt,
    float* __restrict__ out) {
    int r = (blockIdx.x << 8) + threadIdx.x;   // 32 blocks x 256 threads
    __shared__ double sd[256];
    sd[threadIdx.x] = (double)num[r] / (double)Z[r];
    __syncthreads();
    for (int st = 128; st > 0; st >>= 1) {
        if (threadIdx.x < st) sd[threadIdx.x] += sd[threadIdx.x + st];
        __syncthreads();
    }
    if (threadIdx.x == 0) {
        part[blockIdx.x] = sd[0];
        __threadfence();
        unsigned old = atomicAdd(cnt, 1u);
        if (old == 31u) {                // last block folds
            __threadfence();
            double a = 0.0;
            for (int k = 0; k < 32; ++k) a += part[k];
            out[0] = (float)(a / 67108864.0);   // / B^2
        }
    }
}

// ---------------- host launcher -----------------------------------------
extern "C" void kernel_launch(void* const* d_in, const int* in_sizes, int n_in,
                              void* d_out, int out_size, void* d_ws, size_t ws_size,
                              hipStream_t stream) {
    const float* V = (const float*)d_in[0];   // [8192, 512] f32
    const float* E = (const float*)d_in[1];   // [8192, 64]  f32
    float* out = (float*)d_out;
    char* ws = (char*)d_ws;

    float*         n_   = (float*)(ws + 0);            // 32 KB
    float*         ne   = (float*)(ws + 32768);        // 32 KB
    float*         Z    = (float*)(ws + 65536);        // 32 KB (init 1 in k_prep)
    float*         num  = (float*)(ws + 98304);        // 32 KB (init 0 in k_prep)
    unsigned char* VF8  = (unsigned char*)(ws + 131072);// 4 MB fp8 V frags
    _Float16*      EFh  = (_Float16*)(ws + 4325376);   // 1 MB
    double*        part = (double*)(ws + 5373952);     // 256 B
    unsigned*      cnt  = (unsigned*)(ws + 5374208);   // 4 B

    k_prep<<<512, 256, 0, stream>>>(V, E, n_, ne, Z, num, VF8, EFh, cnt);
    k_mega<<<2080, 256, 0, stream>>>(VF8, EFh, ne, n_, Z, num);
    k_red <<<32, 256, 0, stream>>>(Z, num, part, cnt, out);
}